// Round 12
// baseline (73.358 us; speedup 1.0000x reference)
//
#include <hip/hip_runtime.h>

#define NNODES 50000
#define FT 8
#define DD 64
#define KK 16384
#define CAPF 16          // per-(node,type) bucket = exactly one 64B line
#define OVFCAP 32768     // overflow list capacity (P(hit) ~ 1e-7 per cell)
#define NBW 1568         // bitmask words >= ceil(50000/32)

// ---------------- ws layout (int units) ----------------
// cnt     [0,      400000)   per-(node,type) counts   \  zeroed by ONE
// bits    [400000, 401568)   needed-node bitmask       |  hipMemsetAsync
// gtot    [401568, 401572)   [0]=overflow cursor      /
// ovf_key [401572, 434340)   overflow (node*8+f)
// ovf_e   [434340, 467108)   overflow edge id
// sorted  [467120, 467120+50000*8*16)  per-(node,type) buckets (25.6MB, 64B-aligned)

__global__ void mark_kernel(const int* __restrict__ core, unsigned* __restrict__ bits) {
    int k = blockIdx.x * 256 + threadIdx.x;
    if (k >= KK) return;
    int node = core[k];
    atomicOr(&bits[node >> 5], 1u << (node & 31));
}

__global__ void scatter_kernel(const int4* __restrict__ esrc4, const int4* __restrict__ edst4,
                               const int* __restrict__ rawd, const unsigned* __restrict__ bits,
                               int* __restrict__ cnt, int* __restrict__ sorted,
                               int* __restrict__ gtot, int* __restrict__ ovf_key,
                               int* __restrict__ ovf_e, int nE) {
    int t = blockIdx.x * 256 + threadIdx.x;
    int e = t * 8;
    if (e >= nE) return;
    if (e + 7 < nE) {
        int4 sA = esrc4[t * 2], sB = esrc4[t * 2 + 1];
        int4 dA = edst4[t * 2], dB = edst4[t * 2 + 1];
        int sv[8] = {sA.x, sA.y, sA.z, sA.w, sB.x, sB.y, sB.z, sB.w};
        int dv[8] = {dA.x, dA.y, dA.z, dA.w, dB.x, dB.y, dB.z, dB.w};
#pragma unroll
        for (int j = 0; j < 8; ++j) {
            int sn = sv[j];
            if (!((bits[sn >> 5] >> (sn & 31)) & 1u)) continue;
            int cell = sn * FT + rawd[dv[j]];
            int p = atomicAdd(&cnt[cell], 1);
            if (p < CAPF) {
                sorted[(size_t)cell * CAPF + p] = e + j;
            } else {
                int q = atomicAdd(&gtot[0], 1);
                if (q < OVFCAP) { ovf_key[q] = cell; ovf_e[q] = e + j; }
            }
        }
    } else {
        const int* esrc = (const int*)esrc4;
        const int* edst = (const int*)edst4;
        for (; e < nE; ++e) {
            int sn = esrc[e];
            if (!((bits[sn >> 5] >> (sn & 31)) & 1u)) continue;
            int cell = sn * FT + rawd[edst[e]];
            int p = atomicAdd(&cnt[cell], 1);
            if (p < CAPF) {
                sorted[(size_t)cell * CAPF + p] = e;
            } else {
                int q = atomicAdd(&gtot[0], 1);
                if (q < OVFCAP) { ovf_key[q] = cell; ovf_e[q] = e; }
            }
        }
    }
}

#define RL(x) __builtin_amdgcn_readfirstlane(x)

// One wave per k (lane = dim). node = core[k]; direct write to out[k].
// Branchless main f-loop: invalid slots load row 0 (L1-hot) and are masked
// with -inf at the fmax -> one uninterrupted stream of 64 row loads per wave.
__global__ void compute_kernel(const int* __restrict__ core, const int* __restrict__ cnt,
                               const int* __restrict__ sorted, const float* __restrict__ evals,
                               const int* __restrict__ gtot, const int* __restrict__ ovf_key,
                               const int* __restrict__ ovf_e, float* __restrict__ out) {
    int k = (blockIdx.x * blockDim.x + threadIdx.x) >> 6;
    int lane = threadIdx.x & 63;
    if (k >= KK) return;
    int node = RL(core[k]);

    const int4* c4 = (const int4*)(cnt + node * FT);
    int4 cA = c4[0], cB = c4[1];
    int cf[FT] = { RL(cA.x), RL(cA.y), RL(cA.z), RL(cA.w),
                   RL(cB.x), RL(cB.y), RL(cB.z), RL(cB.w) };
    int deg = 0;
    bool anyovf = false, anytail = false;
#pragma unroll
    for (int f = 0; f < FT; ++f) {
        deg += cf[f];
        anyovf |= (cf[f] > CAPF);
        anytail |= (cf[f] > 8);
    }

    // all bucket-id lines loaded up front (each bucket = one 64B line)
    const int4* bkt4 = (const int4*)(sorted + (size_t)node * FT * CAPF);
    int4 id0[FT], id1[FT];
#pragma unroll
    for (int f = 0; f < FT; ++f) { id0[f] = bkt4[f * 4]; id1[f] = bkt4[f * 4 + 1]; }

    float rmax[FT];
#pragma unroll
    for (int f = 0; f < FT; ++f) {
        int n = cf[f];
        // wave-uniform scalar selects: invalid slot -> edge 0 (dummy row, cache-hot)
        int s0 = (n > 0) ? RL(id0[f].x) : 0;
        int s1 = (n > 1) ? RL(id0[f].y) : 0;
        int s2 = (n > 2) ? RL(id0[f].z) : 0;
        int s3 = (n > 3) ? RL(id0[f].w) : 0;
        int s4 = (n > 4) ? RL(id1[f].x) : 0;
        int s5 = (n > 5) ? RL(id1[f].y) : 0;
        int s6 = (n > 6) ? RL(id1[f].z) : 0;
        int s7 = (n > 7) ? RL(id1[f].w) : 0;
        // unconditional loads: uninterrupted issue stream, max MLP
        float v0 = evals[(size_t)s0 * DD + lane];
        float v1 = evals[(size_t)s1 * DD + lane];
        float v2 = evals[(size_t)s2 * DD + lane];
        float v3 = evals[(size_t)s3 * DD + lane];
        float v4 = evals[(size_t)s4 * DD + lane];
        float v5 = evals[(size_t)s5 * DD + lane];
        float v6 = evals[(size_t)s6 * DD + lane];
        float v7 = evals[(size_t)s7 * DD + lane];
        // validity applied at the reduce (v_cndmask, no branches)
        float m0 = fmaxf((n > 0) ? v0 : -INFINITY, (n > 4) ? v4 : -INFINITY);
        float m1 = fmaxf((n > 1) ? v1 : -INFINITY, (n > 5) ? v5 : -INFINITY);
        float m2 = fmaxf((n > 2) ? v2 : -INFINITY, (n > 6) ? v6 : -INFINITY);
        float m3 = fmaxf((n > 3) ? v3 : -INFINITY, (n > 7) ? v7 : -INFINITY);
        rmax[f] = fmaxf(fmaxf(m0, m1), fmaxf(m2, m3));
    }

    if (anytail) {    // ~16% of waves: slots 8..15 of any bucket (after the hot stream)
#pragma unroll
        for (int f = 0; f < FT; ++f) {
            int n = cf[f] < CAPF ? cf[f] : CAPF;
            if (n > 8) {
                const int* bkt = sorted + ((size_t)node * FT + f) * CAPF;
                for (int i = 8; i < n; ++i)
                    rmax[f] = fmaxf(rmax[f], evals[(size_t)RL(bkt[i]) * DD + lane]);
            }
        }
    }

    if (anyovf) {   // cold path: effectively unreachable, kept for correctness
        int no = gtot[0]; if (no > OVFCAP) no = OVFCAP;
        for (int q = 0; q < no; ++q) {
            int key = ovf_key[q];
            if ((key >> 3) != node) continue;
            int fo = key & 7;
            float v = evals[(size_t)ovf_e[q] * DD + lane];
#pragma unroll
            for (int t = 0; t < FT; ++t)
                if (t == fo) rmax[t] = fmaxf(rmax[t], v);
        }
    }

    float* op = out + (size_t)k * (FT * DD) + lane;
#pragma unroll
    for (int f = 0; f < FT; ++f) {
        int matched = cf[f];
        float val;
        if (matched == 0)        val = 0.0f;                 // no matching edge -> 0
        else if (matched < deg)  val = fmaxf(rmax[f], 0.0f); // a masked-to-zero edge exists
        else                     val = rmax[f];              // all edges matched this type
        op[f * DD] = val;
    }
}

extern "C" void kernel_launch(void* const* d_in, const int* in_sizes, int n_in,
                              void* d_out, int out_size, void* d_ws, size_t ws_size,
                              hipStream_t stream) {
    const int*   rawd  = (const int*)d_in[0];
    const int*   esrc  = (const int*)d_in[1];
    const int*   edst  = (const int*)d_in[2];
    const float* evals = (const float*)d_in[3];
    const int*   core  = (const int*)d_in[4];
    int nE = in_sizes[1];

    int* wsi      = (int*)d_ws;
    int* cnt      = wsi;
    unsigned* bits = (unsigned*)(wsi + 400000);
    int* gtot     = wsi + 401568;
    int* ovf_key  = wsi + 401572;
    int* ovf_e    = wsi + 434340;
    int* sorted   = wsi + 467120;   // 64B aligned

    // one memset zeroes cnt | bits | gtot (contiguous)
    hipMemsetAsync(d_ws, 0, (size_t)401572 * sizeof(int), stream);

    mark_kernel<<<(KK + 255) / 256, 256, 0, stream>>>(core, bits);

    int nE8 = (nE + 7) / 8;
    scatter_kernel<<<(nE8 + 255) / 256, 256, 0, stream>>>(
        (const int4*)esrc, (const int4*)edst, rawd, bits, cnt, sorted,
        gtot, ovf_key, ovf_e, nE);

    long long cthreads = (long long)KK * 64;   // one wave per k
    compute_kernel<<<(int)((cthreads + 255) / 256), 256, 0, stream>>>(
        core, cnt, sorted, evals, gtot, ovf_key, ovf_e, (float*)d_out);
}

// Round 13
// 71.056 us; speedup vs baseline: 1.0324x; 1.0324x over previous
//
#include <hip/hip_runtime.h>

#define NNODES 50000
#define FT 8
#define DD 64
#define KK 16384
#define CAPF 16          // per-(node,type) bucket = exactly one 64B line
#define OVFCAP 32768     // overflow list capacity (P(hit) ~ 1e-7 per cell)

// ---------------- ws layout (int units) ----------------
// cnt     [0,      400000)   per-(node,type) counts   \ zeroed in-kernel
// gtot    [400000, 400004)   [0]=overflow cursor      /  (grid-stride)
// tag     [400004, 450004)   node -> k+1 claim; NEVER zeroed (validated reads)
// ovf_key [450004, 482772)   overflow (node*8+f)
// ovf_e   [482772, 515540)   overflow edge id
// sorted  [515552, 515552+50000*8*16)  per-(node,type) buckets (25.6MB, 64B-aligned)

#define ZN 400004        // ints to zero (cnt + gtot)

// Fused init + mark: grid-stride zero of cnt|gtot (no overlap with tag region),
// plus a plain-store tag claim per k. No zeroing of tag needed: scatter
// validates every tag against core[], so stale/poison values are harmless.
__global__ void init_tag_kernel(const int* __restrict__ core,
                                int* __restrict__ zbase, int* __restrict__ tag,
                                int nthreads) {
    int i = blockIdx.x * 256 + threadIdx.x;
    for (int j = i; j < ZN; j += nthreads) zbase[j] = 0;
    if (i < KK) tag[core[i]] = i + 1;     // any winning k is a valid claim
}

__global__ void scatter_kernel(const int4* __restrict__ esrc4, const int4* __restrict__ edst4,
                               const int* __restrict__ rawd, const int* __restrict__ tag,
                               const int* __restrict__ core,
                               int* __restrict__ cnt, int* __restrict__ sorted,
                               int* __restrict__ gtot, int* __restrict__ ovf_key,
                               int* __restrict__ ovf_e, int nE) {
    int t = blockIdx.x * 256 + threadIdx.x;
    int e = t * 8;
    if (e >= nE) return;
    if (e + 7 < nE) {
        int4 sA = esrc4[t * 2], sB = esrc4[t * 2 + 1];
        int4 dA = edst4[t * 2], dB = edst4[t * 2 + 1];
        int sv[8] = {sA.x, sA.y, sA.z, sA.w, sB.x, sB.y, sB.z, sB.w};
        int dv[8] = {dA.x, dA.y, dA.z, dA.w, dB.x, dB.y, dB.z, dB.w};
#pragma unroll
        for (int j = 0; j < 8; ++j) {
            int sn = sv[j];
            unsigned tg = (unsigned)tag[sn];
            if (tg - 1u >= (unsigned)KK) continue;      // stale/poison -> not needed
            if (core[tg - 1] != sn) continue;           // validated claim only
            int cell = sn * FT + rawd[dv[j]];
            int p = atomicAdd(&cnt[cell], 1);
            if (p < CAPF) {
                sorted[(size_t)cell * CAPF + p] = e + j;
            } else {
                int q = atomicAdd(&gtot[0], 1);
                if (q < OVFCAP) { ovf_key[q] = cell; ovf_e[q] = e + j; }
            }
        }
    } else {
        const int* esrc = (const int*)esrc4;
        const int* edst = (const int*)edst4;
        for (; e < nE; ++e) {
            int sn = esrc[e];
            unsigned tg = (unsigned)tag[sn];
            if (tg - 1u >= (unsigned)KK) continue;
            if (core[tg - 1] != sn) continue;
            int cell = sn * FT + rawd[edst[e]];
            int p = atomicAdd(&cnt[cell], 1);
            if (p < CAPF) {
                sorted[(size_t)cell * CAPF + p] = e;
            } else {
                int q = atomicAdd(&gtot[0], 1);
                if (q < OVFCAP) { ovf_key[q] = cell; ovf_e[q] = e; }
            }
        }
    }
}

#define RL(x) __builtin_amdgcn_readfirstlane(x)

// One wave per k (lane = dim). node = core[k]; direct write to out[k].
// 3-hop chain: core/cnt -> bucket ids -> row gathers.
__global__ void compute_kernel(const int* __restrict__ core, const int* __restrict__ cnt,
                               const int* __restrict__ sorted, const float* __restrict__ evals,
                               const int* __restrict__ gtot, const int* __restrict__ ovf_key,
                               const int* __restrict__ ovf_e, float* __restrict__ out) {
    int k = (blockIdx.x * blockDim.x + threadIdx.x) >> 6;
    int lane = threadIdx.x & 63;
    if (k >= KK) return;
    int node = RL(core[k]);

    const int4* c4 = (const int4*)(cnt + node * FT);
    int4 cA = c4[0], cB = c4[1];
    int cf[FT] = { RL(cA.x), RL(cA.y), RL(cA.z), RL(cA.w),
                   RL(cB.x), RL(cB.y), RL(cB.z), RL(cB.w) };
    int deg = 0;
    bool anyovf = false;
#pragma unroll
    for (int f = 0; f < FT; ++f) { deg += cf[f]; anyovf |= (cf[f] > CAPF); }

    // issue all bucket-id loads up front (each bucket = one 64B line; always in-bounds)
    const int4* bkt4 = (const int4*)(sorted + (size_t)node * FT * CAPF);
    int4 id0[FT], id1[FT];
#pragma unroll
    for (int f = 0; f < FT; ++f) { id0[f] = bkt4[f * 4]; id1[f] = bkt4[f * 4 + 1]; }

    float rmax[FT];
#pragma unroll
    for (int f = 0; f < FT; ++f) {
        int n = cf[f] < CAPF ? cf[f] : CAPF;
        float m0 = -INFINITY, m1 = -INFINITY, m2 = -INFINITY, m3 = -INFINITY;
        if (n > 0) m0 = evals[(size_t)RL(id0[f].x) * DD + lane];
        if (n > 1) m1 = evals[(size_t)RL(id0[f].y) * DD + lane];
        if (n > 2) m2 = evals[(size_t)RL(id0[f].z) * DD + lane];
        if (n > 3) m3 = evals[(size_t)RL(id0[f].w) * DD + lane];
        if (n > 4) m0 = fmaxf(m0, evals[(size_t)RL(id1[f].x) * DD + lane]);
        if (n > 5) m1 = fmaxf(m1, evals[(size_t)RL(id1[f].y) * DD + lane]);
        if (n > 6) m2 = fmaxf(m2, evals[(size_t)RL(id1[f].z) * DD + lane]);
        if (n > 7) m3 = fmaxf(m3, evals[(size_t)RL(id1[f].w) * DD + lane]);
        if (n > 8) {   // rare tail (Poisson lambda~4)
            const int* bkt = sorted + ((size_t)node * FT + f) * CAPF;
            for (int i = 8; i < n; ++i)
                m0 = fmaxf(m0, evals[(size_t)RL(bkt[i]) * DD + lane]);
        }
        rmax[f] = fmaxf(fmaxf(m0, m1), fmaxf(m2, m3));
    }

    if (anyovf) {   // cold path: effectively unreachable, kept for correctness
        int no = gtot[0]; if (no > OVFCAP) no = OVFCAP;
        for (int q = 0; q < no; ++q) {
            int key = ovf_key[q];
            if ((key >> 3) != node) continue;
            int fo = key & 7;
            float v = evals[(size_t)ovf_e[q] * DD + lane];
#pragma unroll
            for (int t = 0; t < FT; ++t)
                if (t == fo) rmax[t] = fmaxf(rmax[t], v);
        }
    }

    float* op = out + (size_t)k * (FT * DD) + lane;
#pragma unroll
    for (int f = 0; f < FT; ++f) {
        int matched = cf[f];
        float val;
        if (matched == 0)        val = 0.0f;                 // no matching edge -> 0
        else if (matched < deg)  val = fmaxf(rmax[f], 0.0f); // a masked-to-zero edge exists
        else                     val = rmax[f];              // all edges matched this type
        op[f * DD] = val;
    }
}

extern "C" void kernel_launch(void* const* d_in, const int* in_sizes, int n_in,
                              void* d_out, int out_size, void* d_ws, size_t ws_size,
                              hipStream_t stream) {
    const int*   rawd  = (const int*)d_in[0];
    const int*   esrc  = (const int*)d_in[1];
    const int*   edst  = (const int*)d_in[2];
    const float* evals = (const float*)d_in[3];
    const int*   core  = (const int*)d_in[4];
    int nE = in_sizes[1];

    int* wsi      = (int*)d_ws;
    int* cnt      = wsi;                 // [0, 400000)
    int* gtot     = wsi + 400000;        // [400000, 400004)
    int* tag      = wsi + 400004;        // [400004, 450004) - never zeroed
    int* ovf_key  = wsi + 450004;
    int* ovf_e    = wsi + 482772;
    int* sorted   = wsi + 515552;        // byte offset 2062208: 64B aligned

    const int INIT_BLOCKS = 1024;        // 262144 threads: covers KK, ~2 zero-iters
    init_tag_kernel<<<INIT_BLOCKS, 256, 0, stream>>>(core, cnt, tag, INIT_BLOCKS * 256);

    int nE8 = (nE + 7) / 8;
    scatter_kernel<<<(nE8 + 255) / 256, 256, 0, stream>>>(
        (const int4*)esrc, (const int4*)edst, rawd, tag, core, cnt, sorted,
        gtot, ovf_key, ovf_e, nE);

    long long cthreads = (long long)KK * 64;   // one wave per k
    compute_kernel<<<(int)((cthreads + 255) / 256), 256, 0, stream>>>(
        core, cnt, sorted, evals, gtot, ovf_key, ovf_e, (float*)d_out);
}